// Round 4
// baseline (217.600 us; speedup 1.0000x reference)
//
#include <hip/hip_runtime.h>

#define M_ROWS 16384
#define DIMX   1024
#define CD     12
#define KCB    4096
#define PADW   60   // padded dwords per float4-position fragment (48 data + 12 pad)

// ---------- Kernel A: h = x @ W_in + b_in ; writes h and oidx ----------
// Arithmetic (FMA order k,e,d; butterfly ofs 1..32; +bin at end) is bit-identical
// to the round-1/2 version that produced exact index match.
__global__ __launch_bounds__(256, 2) void k_hproj(
    const float* __restrict__ x, const float* __restrict__ Win,
    const float* __restrict__ bin, float* __restrict__ h, float* __restrict__ oidx)
{
  __shared__ __align__(16) float w[256 * PADW];   // 60 KB, conflict-free stride
  for (int f = threadIdx.x; f < 256 * 12; f += 256) {
    const int P = f / 12, c = f % 12;
    float4 v = reinterpret_cast<const float4*>(Win)[f];
    *reinterpret_cast<float4*>(&w[P * PADW + 4 * c]) = v;
  }
  __syncthreads();

  const int wave = threadIdx.x >> 6;
  const int lane = threadIdx.x & 63;
  const int g    = blockIdx.x * 4 + wave;         // 0..2047, 8 rows per wave

  float bb[CD];
#pragma unroll
  for (int d = 0; d < CD; ++d) bb[d] = bin[d];

  for (int it = 0; it < 4; ++it) {                // 2 rows per iteration
    const int row0 = g * 8 + it * 2;
    const float4* xr0 = reinterpret_cast<const float4*>(x + (size_t)row0 * DIMX);
    const float4* xr1 = reinterpret_cast<const float4*>(x + (size_t)(row0 + 1) * DIMX);
    float a0[CD], a1[CD];
#pragma unroll
    for (int d = 0; d < CD; ++d) { a0[d] = 0.f; a1[d] = 0.f; }

#pragma unroll
    for (int k = 0; k < 4; ++k) {
      const int P = lane + 64 * k;
      float4 xv0 = xr0[P];
      float4 xv1 = xr1[P];
      const float4* wf = reinterpret_cast<const float4*>(&w[P * PADW]);
      float4 wq[12];
#pragma unroll
      for (int c = 0; c < 12; ++c) wq[c] = wf[c];
      const float* wfl = reinterpret_cast<const float*>(wq);
      float xe0[4] = {xv0.x, xv0.y, xv0.z, xv0.w};
      float xe1[4] = {xv1.x, xv1.y, xv1.z, xv1.w};
#pragma unroll
      for (int e = 0; e < 4; ++e)
#pragma unroll
        for (int d = 0; d < CD; ++d) {
          const float wv = wfl[e * CD + d];
          a0[d] = fmaf(xe0[e], wv, a0[d]);
          a1[d] = fmaf(xe1[e], wv, a1[d]);
        }
    }
#pragma unroll
    for (int ofs = 1; ofs < 64; ofs <<= 1)
#pragma unroll
      for (int d = 0; d < CD; ++d) {
        a0[d] += __shfl_xor(a0[d], ofs, 64);
        a1[d] += __shfl_xor(a1[d], ofs, 64);
      }

    if (lane == 0) {
      int i0 = 0, i1 = 0;
#pragma unroll
      for (int d = 0; d < CD; ++d) {
        const float h0 = a0[d] + bb[d];
        const float h1 = a1[d] + bb[d];
        h[(size_t)row0 * CD + d]       = h0;
        h[(size_t)(row0 + 1) * CD + d] = h1;
        i0 |= (h0 > 0.f) ? (1 << d) : 0;
        i1 |= (h1 > 0.f) ? (1 << d) : 0;
      }
      oidx[row0]     = (float)i0;
      oidx[row0 + 1] = (float)i1;
    }
  }
}

// ---------- Kernel B: out = sign(h) @ W_out + b_out (signs from oidx) ----------
__global__ __launch_bounds__(256, 2) void k_out(
    const float* __restrict__ Wout, const float* __restrict__ bout,
    const float* __restrict__ oidx, float* __restrict__ out, int rows_pb)
{
  const int t = threadIdx.x;
  float wreg[CD][4];
#pragma unroll
  for (int d = 0; d < CD; ++d) {
    float4 v = *reinterpret_cast<const float4*>(Wout + d * DIMX + 4 * t);
    wreg[d][0] = v.x; wreg[d][1] = v.y; wreg[d][2] = v.z; wreg[d][3] = v.w;
  }
  float4 b4 = *reinterpret_cast<const float4*>(bout + 4 * t);

  const int row0 = blockIdx.x * rows_pb;
  for (int i = 0; i < rows_pb; ++i) {
    const int row = row0 + i;
    const int idx = (int)oidx[row];               // block-uniform scalar load
    float o0 = b4.x, o1 = b4.y, o2 = b4.z, o3 = b4.w;
#pragma unroll
    for (int d = 0; d < CD; ++d) {
      const float s = ((idx >> d) & 1) ? 1.f : -1.f;
      o0 = fmaf(s, wreg[d][0], o0);
      o1 = fmaf(s, wreg[d][1], o1);
      o2 = fmaf(s, wreg[d][2], o2);
      o3 = fmaf(s, wreg[d][3], o3);
    }
    reinterpret_cast<float4*>(out + (size_t)row * DIMX)[t] = make_float4(o0, o1, o2, o3);
  }
}

// ---------- Kernel C: entropy + commit + factorized histogram ----------
// Wave per row-group; lane owns codes j = m*64 + lane, p_j = A_lane*C[m&7]*D[m>>3].
// acc[64] MUST stay in VGPRs: every access fully unrolled (compile-time index).
__global__ __launch_bounds__(256, 2) void k_ent(
    const float* __restrict__ h, float* __restrict__ hist_part,
    float* __restrict__ pse, float* __restrict__ com, int rpw)
{
  __shared__ float lh[KCB];                       // 16 KiB block histogram
  const int lane = threadIdx.x & 63;
  const int wid  = threadIdx.x >> 6;

  for (int i = threadIdx.x; i < KCB; i += 256) lh[i] = 0.f;
  __syncthreads();

  float acc[64];
#pragma unroll
  for (int m = 0; m < 64; ++m) acc[m] = 0.f;
  float pse_acc = 0.f, com_acc = 0.f;

  const int r0 = (blockIdx.x * 4 + wid) * rpw;
  for (int i = 0; i < rpw; ++i) {
    const int row = r0 + i;
    float qv = 0.f;
    if (lane < CD) {
      const float hv = h[(size_t)row * CD + lane];
      const float ax  = fabsf(40.f * hv);
      const float e2  = __expf(-ax);
      const float s1  = 1.f + e2;
      const float inv = 1.f / s1;
      qv = (hv > 0.f) ? inv : e2 * inv;           // sigmoid(40 h)
      pse_acc += __logf(s1) + ax * e2 * inv;      // per-dim entropy term
      const float dd = fabsf(hv) - 1.f;
      com_acc += dd * dd;
    }
    float qb[CD];
#pragma unroll
    for (int d = 0; d < CD; ++d) qb[d] = __shfl(qv, d, 64);

    float A = 1.f;
#pragma unroll
    for (int d = 0; d < 6; ++d) A *= ((lane >> d) & 1) ? qb[d] : (1.f - qb[d]);

    float C[8], D[8];
    C[0] = 1.f; D[0] = 1.f;
#pragma unroll
    for (int d = 0; d < 3; ++d) {
      const float qc = qb[6 + d], qd = qb[9 + d];
#pragma unroll
      for (int j2 = 0; j2 < (1 << d); ++j2) {
        C[j2 + (1 << d)] = C[j2] * qc; C[j2] *= (1.f - qc);
        D[j2 + (1 << d)] = D[j2] * qd; D[j2] *= (1.f - qd);
      }
    }
    float E[8];
#pragma unroll
    for (int k = 0; k < 8; ++k) E[k] = A * C[k];
#pragma unroll
    for (int m = 0; m < 64; ++m)
      acc[m] = fmaf(E[m & 7], D[m >> 3], acc[m]);
  }

  // combine the block's 4 waves in LDS (ds_add_f32), fully unrolled
#pragma unroll
  for (int m = 0; m < 64; ++m)
    atomicAdd(&lh[m * 64 + lane], acc[m]);
  __syncthreads();

  // one coalesced 16 KiB store per block
  float4* hp = reinterpret_cast<float4*>(hist_part + (size_t)blockIdx.x * KCB);
  const float4* ls = reinterpret_cast<const float4*>(lh);
  for (int i = threadIdx.x; i < KCB / 4; i += 256) hp[i] = ls[i];

#pragma unroll
  for (int ofs = 1; ofs < 64; ofs <<= 1) {
    pse_acc += __shfl_xor(pse_acc, ofs, 64);
    com_acc += __shfl_xor(com_acc, ofs, 64);
  }
  if (lane == 0) { atomicAdd(pse, pse_acc); atomicAdd(com, com_acc); }
}

// ---------- Kernel D1: partial slab reduction (chunked) ----------
__global__ __launch_bounds__(256) void k_hr1(
    const float* __restrict__ hist_part, float* __restrict__ part2,
    int nslab)
{
  const int j     = (blockIdx.x & 15) * 256 + threadIdx.x;
  const int chunk = blockIdx.x >> 4;              // 0..15
  const int per   = nslab >> 4;
  const int b0    = chunk * per;
  float acc = 0.f;
#pragma unroll 4
  for (int b = 0; b < per; ++b)
    acc += hist_part[(size_t)(b0 + b) * KCB + j];
  part2[(size_t)chunk * KCB + j] = acc;
}

// ---------- Kernel D2: final codebook entropy ----------
__global__ __launch_bounds__(256) void k_hr2(
    const float* __restrict__ part2, float* __restrict__ cbe)
{
  const int j = blockIdx.x * 256 + threadIdx.x;
  float acc = 0.f;
#pragma unroll
  for (int c = 0; c < 16; ++c) acc += part2[(size_t)c * KCB + j];
  const float a = acc * (1.f / 16384.f);
  float term = -a * __logf(a + 1e-10f);
#pragma unroll
  for (int ofs = 1; ofs < 64; ofs <<= 1) term += __shfl_xor(term, ofs, 64);
  __shared__ float sw[4];
  if ((threadIdx.x & 63) == 0) sw[threadIdx.x >> 6] = term;
  __syncthreads();
  if (threadIdx.x == 0) atomicAdd(cbe, sw[0] + sw[1] + sw[2] + sw[3]);
}

// ---------- Kernel E: combine scalars ----------
__global__ void k_aux(const float* __restrict__ pse, const float* __restrict__ com,
                      const float* __restrict__ cbe, float* __restrict__ aux)
{
  aux[0] = pse[0] * (1.f / 16384.f) - cbe[0] + com[0] * (1.f / 196608.f);
}

extern "C" void kernel_launch(void* const* d_in, const int* in_sizes, int n_in,
                              void* d_out, int out_size, void* d_ws, size_t ws_size,
                              hipStream_t stream)
{
  const float* x    = (const float*)d_in[0];
  const float* Win  = (const float*)d_in[1];
  const float* bin  = (const float*)d_in[2];
  const float* Wout = (const float*)d_in[3];
  const float* bout = (const float*)d_in[4];

  float* out  = (float*)d_out;                       // [16384 x 1024]
  float* oidx = out + (size_t)M_ROWS * DIMX;         // [16384]
  float* aux  = oidx + M_ROWS;                       // [1]

  float* ws        = (float*)d_ws;
  float* h         = ws;                             // 196608 floats
  float* scal      = ws + (size_t)M_ROWS * CD;       // pse, com, cbe (pad 16)
  float* pse       = scal;
  float* com       = scal + 1;
  float* cbe       = scal + 2;
  float* part2     = scal + 16;                      // 16 * 4096 floats
  float* hist_part = part2 + 16 * KCB;               // nblk * 4096 floats

  // one histogram slab per BLOCK (4 waves combined in LDS)
  int nblk = 1024;
  while (nblk > 256 &&
         ((size_t)M_ROWS * CD + 16 + 16 * KCB + (size_t)nblk * KCB) * 4 > ws_size)
    nblk >>= 1;
  const int rpw = M_ROWS / (nblk * 4);               // rows per wave

  hipMemsetAsync(scal, 0, 3 * sizeof(float), stream);
  k_hproj<<<512, 256, 0, stream>>>(x, Win, bin, h, oidx);
  k_ent  <<<nblk, 256, 0, stream>>>(h, hist_part, pse, com, rpw);   // h still L2-warm
  k_out  <<<512, 256, 0, stream>>>(Wout, bout, oidx, out, M_ROWS / 512);
  k_hr1  <<<256, 256, 0, stream>>>(hist_part, part2, nblk);
  k_hr2  <<<KCB / 256, 256, 0, stream>>>(part2, cbe);
  k_aux  <<<1, 1, 0, stream>>>(pse, com, cbe, aux);
}

// Round 5
// 217.491 us; speedup vs baseline: 1.0005x; 1.0005x over previous
//
#include <hip/hip_runtime.h>

#define M_ROWS 16384
#define DIMX   1024
#define CD     12
#define KCB    4096
#define PADW   60   // padded dwords per float4-position fragment (48 data + 12 pad)

// ---------- Kernel A: h = x @ W_in + b_in ; writes h and oidx ----------
// Arithmetic (FMA order k,e,d; butterfly ofs 1..32; +bin at end) is bit-identical
// to the round-1/2 version that produced exact index match.
__global__ __launch_bounds__(256, 2) void k_hproj(
    const float* __restrict__ x, const float* __restrict__ Win,
    const float* __restrict__ bin, float* __restrict__ h, float* __restrict__ oidx)
{
  __shared__ __align__(16) float w[256 * PADW];   // 60 KB, conflict-free stride
  for (int f = threadIdx.x; f < 256 * 12; f += 256) {
    const int P = f / 12, c = f % 12;
    float4 v = reinterpret_cast<const float4*>(Win)[f];
    *reinterpret_cast<float4*>(&w[P * PADW + 4 * c]) = v;
  }
  __syncthreads();

  const int wave = threadIdx.x >> 6;
  const int lane = threadIdx.x & 63;
  const int g    = blockIdx.x * 4 + wave;         // 0..2047, 8 rows per wave

  float bb[CD];
#pragma unroll
  for (int d = 0; d < CD; ++d) bb[d] = bin[d];

  for (int it = 0; it < 4; ++it) {                // 2 rows per iteration
    const int row0 = g * 8 + it * 2;
    const float4* xr0 = reinterpret_cast<const float4*>(x + (size_t)row0 * DIMX);
    const float4* xr1 = reinterpret_cast<const float4*>(x + (size_t)(row0 + 1) * DIMX);
    float a0[CD], a1[CD];
#pragma unroll
    for (int d = 0; d < CD; ++d) { a0[d] = 0.f; a1[d] = 0.f; }

#pragma unroll
    for (int k = 0; k < 4; ++k) {
      const int P = lane + 64 * k;
      float4 xv0 = xr0[P];
      float4 xv1 = xr1[P];
      const float4* wf = reinterpret_cast<const float4*>(&w[P * PADW]);
      float4 wq[12];
#pragma unroll
      for (int c = 0; c < 12; ++c) wq[c] = wf[c];
      const float* wfl = reinterpret_cast<const float*>(wq);
      float xe0[4] = {xv0.x, xv0.y, xv0.z, xv0.w};
      float xe1[4] = {xv1.x, xv1.y, xv1.z, xv1.w};
#pragma unroll
      for (int e = 0; e < 4; ++e)
#pragma unroll
        for (int d = 0; d < CD; ++d) {
          const float wv = wfl[e * CD + d];
          a0[d] = fmaf(xe0[e], wv, a0[d]);
          a1[d] = fmaf(xe1[e], wv, a1[d]);
        }
    }
#pragma unroll
    for (int ofs = 1; ofs < 64; ofs <<= 1)
#pragma unroll
      for (int d = 0; d < CD; ++d) {
        a0[d] += __shfl_xor(a0[d], ofs, 64);
        a1[d] += __shfl_xor(a1[d], ofs, 64);
      }

    if (lane == 0) {
      int i0 = 0, i1 = 0;
#pragma unroll
      for (int d = 0; d < CD; ++d) {
        const float h0 = a0[d] + bb[d];
        const float h1 = a1[d] + bb[d];
        h[(size_t)row0 * CD + d]       = h0;
        h[(size_t)(row0 + 1) * CD + d] = h1;
        i0 |= (h0 > 0.f) ? (1 << d) : 0;
        i1 |= (h1 > 0.f) ? (1 << d) : 0;
      }
      oidx[row0]     = (float)i0;
      oidx[row0 + 1] = (float)i1;
    }
  }
}

// ---------- Kernel B: out = sign(h) @ W_out + b_out (signs from oidx) ----------
__global__ __launch_bounds__(256, 2) void k_out(
    const float* __restrict__ Wout, const float* __restrict__ bout,
    const float* __restrict__ oidx, float* __restrict__ out, int rows_pb)
{
  const int t = threadIdx.x;
  float wreg[CD][4];
#pragma unroll
  for (int d = 0; d < CD; ++d) {
    float4 v = *reinterpret_cast<const float4*>(Wout + d * DIMX + 4 * t);
    wreg[d][0] = v.x; wreg[d][1] = v.y; wreg[d][2] = v.z; wreg[d][3] = v.w;
  }
  float4 b4 = *reinterpret_cast<const float4*>(bout + 4 * t);

  const int row0 = blockIdx.x * rows_pb;
  for (int i = 0; i < rows_pb; ++i) {
    const int row = row0 + i;
    const int idx = (int)oidx[row];               // block-uniform scalar load
    float o0 = b4.x, o1 = b4.y, o2 = b4.z, o3 = b4.w;
#pragma unroll
    for (int d = 0; d < CD; ++d) {
      const float s = ((idx >> d) & 1) ? 1.f : -1.f;
      o0 = fmaf(s, wreg[d][0], o0);
      o1 = fmaf(s, wreg[d][1], o1);
      o2 = fmaf(s, wreg[d][2], o2);
      o3 = fmaf(s, wreg[d][3], o3);
    }
    reinterpret_cast<float4*>(out + (size_t)row * DIMX)[t] = make_float4(o0, o1, o2, o3);
  }
}

// ---------- Kernel C: entropy + commit + factorized histogram ----------
// Wave per row-group; lane owns codes j = m*64 + lane, p_j = A*C[m&7]*D[m>>3].
// NO indexable arrays in the hot loop — 64 named accumulators so nothing can
// land in scratch (round-4 lesson: #pragma unroll did NOT promote acc[64]).
__global__ __launch_bounds__(256, 2) void k_ent(
    const float* __restrict__ h, float* __restrict__ hist_part,
    float* __restrict__ pse, float* __restrict__ com, int rpw)
{
  __shared__ float lh[KCB];                       // 16 KiB block histogram
  const int lane = threadIdx.x & 63;
  const int wid  = threadIdx.x >> 6;

  for (int i = threadIdx.x; i < KCB; i += 256) lh[i] = 0.f;
  __syncthreads();

  float a0=0.f,a1=0.f,a2=0.f,a3=0.f,a4=0.f,a5=0.f,a6=0.f,a7=0.f,
        a8=0.f,a9=0.f,a10=0.f,a11=0.f,a12=0.f,a13=0.f,a14=0.f,a15=0.f,
        a16=0.f,a17=0.f,a18=0.f,a19=0.f,a20=0.f,a21=0.f,a22=0.f,a23=0.f,
        a24=0.f,a25=0.f,a26=0.f,a27=0.f,a28=0.f,a29=0.f,a30=0.f,a31=0.f,
        a32=0.f,a33=0.f,a34=0.f,a35=0.f,a36=0.f,a37=0.f,a38=0.f,a39=0.f,
        a40=0.f,a41=0.f,a42=0.f,a43=0.f,a44=0.f,a45=0.f,a46=0.f,a47=0.f,
        a48=0.f,a49=0.f,a50=0.f,a51=0.f,a52=0.f,a53=0.f,a54=0.f,a55=0.f,
        a56=0.f,a57=0.f,a58=0.f,a59=0.f,a60=0.f,a61=0.f,a62=0.f,a63=0.f;
  float pse_acc = 0.f, com_acc = 0.f;

  const int r0 = (blockIdx.x * 4 + wid) * rpw;
  for (int i = 0; i < rpw; ++i) {
    const int row = r0 + i;
    float qv = 0.f;
    if (lane < CD) {
      const float hv = h[(size_t)row * CD + lane];
      const float ax  = fabsf(40.f * hv);
      const float e2  = __expf(-ax);
      const float s1  = 1.f + e2;
      const float inv = 1.f / s1;
      qv = (hv > 0.f) ? inv : e2 * inv;           // sigmoid(40 h)
      pse_acc += __logf(s1) + ax * e2 * inv;      // per-dim entropy term
      const float dd = fabsf(hv) - 1.f;
      com_acc += dd * dd;
    }
    const float q0  = __shfl(qv, 0, 64),  q1  = __shfl(qv, 1, 64);
    const float q2  = __shfl(qv, 2, 64),  q3  = __shfl(qv, 3, 64);
    const float q4  = __shfl(qv, 4, 64),  q5  = __shfl(qv, 5, 64);
    const float q6  = __shfl(qv, 6, 64),  q7  = __shfl(qv, 7, 64);
    const float q8  = __shfl(qv, 8, 64),  q9  = __shfl(qv, 9, 64);
    const float q10 = __shfl(qv, 10, 64), q11 = __shfl(qv, 11, 64);

    float A = ((lane >> 0) & 1) ? q0 : 1.f - q0;
    A      *= ((lane >> 1) & 1) ? q1 : 1.f - q1;
    A      *= ((lane >> 2) & 1) ? q2 : 1.f - q2;
    A      *= ((lane >> 3) & 1) ? q3 : 1.f - q3;
    A      *= ((lane >> 4) & 1) ? q4 : 1.f - q4;
    A      *= ((lane >> 5) & 1) ? q5 : 1.f - q5;

    // C over dims 6..8 (named, straight-line)
    const float t6 = 1.f - q6, t7 = 1.f - q7, t8 = 1.f - q8;
    const float u0 = t6 * t7, u1 = q6 * t7, u2 = t6 * q7, u3 = q6 * q7;
    // E = A * C
    const float E0 = A * (u0 * t8), E1 = A * (u1 * t8), E2 = A * (u2 * t8), E3 = A * (u3 * t8);
    const float E4 = A * (u0 * q8), E5 = A * (u1 * q8), E6 = A * (u2 * q8), E7 = A * (u3 * q8);
    // D over dims 9..11 (named, straight-line)
    const float t9 = 1.f - q9, t10 = 1.f - q10, t11 = 1.f - q11;
    const float v0 = t9 * t10, v1 = q9 * t10, v2 = t9 * q10, v3 = q9 * q10;
    const float D0 = v0 * t11, D1 = v1 * t11, D2 = v2 * t11, D3 = v3 * t11;
    const float D4 = v0 * q11, D5 = v1 * q11, D6 = v2 * q11, D7 = v3 * q11;

    a0  = fmaf(E0, D0, a0);  a1  = fmaf(E1, D0, a1);  a2  = fmaf(E2, D0, a2);  a3  = fmaf(E3, D0, a3);
    a4  = fmaf(E4, D0, a4);  a5  = fmaf(E5, D0, a5);  a6  = fmaf(E6, D0, a6);  a7  = fmaf(E7, D0, a7);
    a8  = fmaf(E0, D1, a8);  a9  = fmaf(E1, D1, a9);  a10 = fmaf(E2, D1, a10); a11 = fmaf(E3, D1, a11);
    a12 = fmaf(E4, D1, a12); a13 = fmaf(E5, D1, a13); a14 = fmaf(E6, D1, a14); a15 = fmaf(E7, D1, a15);
    a16 = fmaf(E0, D2, a16); a17 = fmaf(E1, D2, a17); a18 = fmaf(E2, D2, a18); a19 = fmaf(E3, D2, a19);
    a20 = fmaf(E4, D2, a20); a21 = fmaf(E5, D2, a21); a22 = fmaf(E6, D2, a22); a23 = fmaf(E7, D2, a23);
    a24 = fmaf(E0, D3, a24); a25 = fmaf(E1, D3, a25); a26 = fmaf(E2, D3, a26); a27 = fmaf(E3, D3, a27);
    a28 = fmaf(E4, D3, a28); a29 = fmaf(E5, D3, a29); a30 = fmaf(E6, D3, a30); a31 = fmaf(E7, D3, a31);
    a32 = fmaf(E0, D4, a32); a33 = fmaf(E1, D4, a33); a34 = fmaf(E2, D4, a34); a35 = fmaf(E3, D4, a35);
    a36 = fmaf(E4, D4, a36); a37 = fmaf(E5, D4, a37); a38 = fmaf(E6, D4, a38); a39 = fmaf(E7, D4, a39);
    a40 = fmaf(E0, D5, a40); a41 = fmaf(E1, D5, a41); a42 = fmaf(E2, D5, a42); a43 = fmaf(E3, D5, a43);
    a44 = fmaf(E4, D5, a44); a45 = fmaf(E5, D5, a45); a46 = fmaf(E6, D5, a46); a47 = fmaf(E7, D5, a47);
    a48 = fmaf(E0, D6, a48); a49 = fmaf(E1, D6, a49); a50 = fmaf(E2, D6, a50); a51 = fmaf(E3, D6, a51);
    a52 = fmaf(E4, D6, a52); a53 = fmaf(E5, D6, a53); a54 = fmaf(E6, D6, a54); a55 = fmaf(E7, D6, a55);
    a56 = fmaf(E0, D7, a56); a57 = fmaf(E1, D7, a57); a58 = fmaf(E2, D7, a58); a59 = fmaf(E3, D7, a59);
    a60 = fmaf(E4, D7, a60); a61 = fmaf(E5, D7, a61); a62 = fmaf(E6, D7, a62); a63 = fmaf(E7, D7, a63);
  }

  // combine the block's 4 waves into the LDS histogram (ds_add_f32)
  float* lp = &lh[lane];
  atomicAdd(lp +  0*64, a0);  atomicAdd(lp +  1*64, a1);  atomicAdd(lp +  2*64, a2);  atomicAdd(lp +  3*64, a3);
  atomicAdd(lp +  4*64, a4);  atomicAdd(lp +  5*64, a5);  atomicAdd(lp +  6*64, a6);  atomicAdd(lp +  7*64, a7);
  atomicAdd(lp +  8*64, a8);  atomicAdd(lp +  9*64, a9);  atomicAdd(lp + 10*64, a10); atomicAdd(lp + 11*64, a11);
  atomicAdd(lp + 12*64, a12); atomicAdd(lp + 13*64, a13); atomicAdd(lp + 14*64, a14); atomicAdd(lp + 15*64, a15);
  atomicAdd(lp + 16*64, a16); atomicAdd(lp + 17*64, a17); atomicAdd(lp + 18*64, a18); atomicAdd(lp + 19*64, a19);
  atomicAdd(lp + 20*64, a20); atomicAdd(lp + 21*64, a21); atomicAdd(lp + 22*64, a22); atomicAdd(lp + 23*64, a23);
  atomicAdd(lp + 24*64, a24); atomicAdd(lp + 25*64, a25); atomicAdd(lp + 26*64, a26); atomicAdd(lp + 27*64, a27);
  atomicAdd(lp + 28*64, a28); atomicAdd(lp + 29*64, a29); atomicAdd(lp + 30*64, a30); atomicAdd(lp + 31*64, a31);
  atomicAdd(lp + 32*64, a32); atomicAdd(lp + 33*64, a33); atomicAdd(lp + 34*64, a34); atomicAdd(lp + 35*64, a35);
  atomicAdd(lp + 36*64, a36); atomicAdd(lp + 37*64, a37); atomicAdd(lp + 38*64, a38); atomicAdd(lp + 39*64, a39);
  atomicAdd(lp + 40*64, a40); atomicAdd(lp + 41*64, a41); atomicAdd(lp + 42*64, a42); atomicAdd(lp + 43*64, a43);
  atomicAdd(lp + 44*64, a44); atomicAdd(lp + 45*64, a45); atomicAdd(lp + 46*64, a46); atomicAdd(lp + 47*64, a47);
  atomicAdd(lp + 48*64, a48); atomicAdd(lp + 49*64, a49); atomicAdd(lp + 50*64, a50); atomicAdd(lp + 51*64, a51);
  atomicAdd(lp + 52*64, a52); atomicAdd(lp + 53*64, a53); atomicAdd(lp + 54*64, a54); atomicAdd(lp + 55*64, a55);
  atomicAdd(lp + 56*64, a56); atomicAdd(lp + 57*64, a57); atomicAdd(lp + 58*64, a58); atomicAdd(lp + 59*64, a59);
  atomicAdd(lp + 60*64, a60); atomicAdd(lp + 61*64, a61); atomicAdd(lp + 62*64, a62); atomicAdd(lp + 63*64, a63);
  __syncthreads();

  // one coalesced 16 KiB store per block
  float4* hp = reinterpret_cast<float4*>(hist_part + (size_t)blockIdx.x * KCB);
  const float4* ls = reinterpret_cast<const float4*>(lh);
  for (int i = threadIdx.x; i < KCB / 4; i += 256) hp[i] = ls[i];

#pragma unroll
  for (int ofs = 1; ofs < 64; ofs <<= 1) {
    pse_acc += __shfl_xor(pse_acc, ofs, 64);
    com_acc += __shfl_xor(com_acc, ofs, 64);
  }
  if (lane == 0) { atomicAdd(pse, pse_acc); atomicAdd(com, com_acc); }
}

// ---------- Kernel D1: partial slab reduction (chunked) ----------
__global__ __launch_bounds__(256) void k_hr1(
    const float* __restrict__ hist_part, float* __restrict__ part2,
    int nslab)
{
  const int j     = (blockIdx.x & 15) * 256 + threadIdx.x;
  const int chunk = blockIdx.x >> 4;              // 0..15
  const int per   = nslab >> 4;
  const int b0    = chunk * per;
  float acc = 0.f;
#pragma unroll 4
  for (int b = 0; b < per; ++b)
    acc += hist_part[(size_t)(b0 + b) * KCB + j];
  part2[(size_t)chunk * KCB + j] = acc;
}

// ---------- Kernel D2: final codebook entropy ----------
__global__ __launch_bounds__(256) void k_hr2(
    const float* __restrict__ part2, float* __restrict__ cbe)
{
  const int j = blockIdx.x * 256 + threadIdx.x;
  float acc = 0.f;
#pragma unroll
  for (int c = 0; c < 16; ++c) acc += part2[(size_t)c * KCB + j];
  const float a = acc * (1.f / 16384.f);
  float term = -a * __logf(a + 1e-10f);
#pragma unroll
  for (int ofs = 1; ofs < 64; ofs <<= 1) term += __shfl_xor(term, ofs, 64);
  __shared__ float sw[4];
  if ((threadIdx.x & 63) == 0) sw[threadIdx.x >> 6] = term;
  __syncthreads();
  if (threadIdx.x == 0) atomicAdd(cbe, sw[0] + sw[1] + sw[2] + sw[3]);
}

// ---------- Kernel E: combine scalars ----------
__global__ void k_aux(const float* __restrict__ pse, const float* __restrict__ com,
                      const float* __restrict__ cbe, float* __restrict__ aux)
{
  aux[0] = pse[0] * (1.f / 16384.f) - cbe[0] + com[0] * (1.f / 196608.f);
}

extern "C" void kernel_launch(void* const* d_in, const int* in_sizes, int n_in,
                              void* d_out, int out_size, void* d_ws, size_t ws_size,
                              hipStream_t stream)
{
  const float* x    = (const float*)d_in[0];
  const float* Win  = (const float*)d_in[1];
  const float* bin  = (const float*)d_in[2];
  const float* Wout = (const float*)d_in[3];
  const float* bout = (const float*)d_in[4];

  float* out  = (float*)d_out;                       // [16384 x 1024]
  float* oidx = out + (size_t)M_ROWS * DIMX;         // [16384]
  float* aux  = oidx + M_ROWS;                       // [1]

  float* ws        = (float*)d_ws;
  float* h         = ws;                             // 196608 floats
  float* scal      = ws + (size_t)M_ROWS * CD;       // pse, com, cbe (pad 16)
  float* pse       = scal;
  float* com       = scal + 1;
  float* cbe       = scal + 2;
  float* part2     = scal + 16;                      // 16 * 4096 floats
  float* hist_part = part2 + 16 * KCB;               // nblk * 4096 floats

  // one histogram slab per BLOCK (4 waves combined in LDS)
  int nblk = 1024;
  while (nblk > 256 &&
         ((size_t)M_ROWS * CD + 16 + 16 * KCB + (size_t)nblk * KCB) * 4 > ws_size)
    nblk >>= 1;
  const int rpw = M_ROWS / (nblk * 4);               // rows per wave

  hipMemsetAsync(scal, 0, 3 * sizeof(float), stream);
  k_hproj<<<512, 256, 0, stream>>>(x, Win, bin, h, oidx);
  k_ent  <<<nblk, 256, 0, stream>>>(h, hist_part, pse, com, rpw);   // h still L2-warm
  k_out  <<<512, 256, 0, stream>>>(Wout, bout, oidx, out, M_ROWS / 512);
  k_hr1  <<<256, 256, 0, stream>>>(hist_part, part2, nblk);
  k_hr2  <<<KCB / 256, 256, 0, stream>>>(part2, cbe);
  k_aux  <<<1, 1, 0, stream>>>(pse, com, cbe, aux);
}